// Round 1
// baseline (55.580 us; speedup 1.0000x reference)
//
#include <hip/hip_runtime.h>

// Bilinear interpolation gather:
//   data:  (N=8, H=1024, W=1024, C=32) f32
//   sub_x: (N, P=65536) f32, sub_y: (N, P) f32
//   out:   (N, P, C) f32
//
// Mapping: 8 lanes per sample; lane q in [0,8) handles channels [4q, 4q+4)
// as one float4. Each pixel's 32-channel row = 128 B = 8 lanes x 16 B,
// fully coalesced. v00/v01 are adjacent pixels -> contiguous 256 B segment.

constexpr int kH = 1024;
constexpr int kW = 1024;
constexpr int kC4 = 8;          // C/4 float4s per pixel
constexpr int kLogP = 16;       // P = 65536

__global__ __launch_bounds__(256) void interp_kernel(
    const float4* __restrict__ data,
    const float*  __restrict__ sub_x,
    const float*  __restrict__ sub_y,
    float4*       __restrict__ out,
    int n_samples)
{
    int gtid = blockIdx.x * blockDim.x + threadIdx.x;
    int s = gtid >> 3;          // sample index (n*P + p)
    int q = gtid & 7;           // float4 slot within channel row
    if (s >= n_samples) return;

    int n = s >> kLogP;         // image index

    float sx = sub_x[s];
    float sy = sub_y[s];
    float x0f = floorf(sx);
    float y0f = floorf(sy);
    float wx = sx - x0f;
    float wy = sy - y0f;

    int x0 = (int)fminf(fmaxf(x0f,        0.0f), (float)(kW - 1));
    int x1 = (int)fminf(fmaxf(x0f + 1.0f, 0.0f), (float)(kW - 1));
    int y0 = (int)fminf(fmaxf(y0f,        0.0f), (float)(kH - 1));
    int y1 = (int)fminf(fmaxf(y0f + 1.0f, 0.0f), (float)(kH - 1));

    long base_n = (long)n * kH * kW * kC4;
    long row0   = base_n + (long)y0 * (kW * kC4);
    long row1   = base_n + (long)y1 * (kW * kC4);

    float4 v00 = data[row0 + x0 * kC4 + q];
    float4 v01 = data[row0 + x1 * kC4 + q];
    float4 v10 = data[row1 + x0 * kC4 + q];
    float4 v11 = data[row1 + x1 * kC4 + q];

    float w00 = (1.0f - wx) * (1.0f - wy);
    float w01 = wx * (1.0f - wy);
    float w10 = (1.0f - wx) * wy;
    float w11 = wx * wy;

    float4 r;
    r.x = v00.x * w00 + v01.x * w01 + v10.x * w10 + v11.x * w11;
    r.y = v00.y * w00 + v01.y * w01 + v10.y * w10 + v11.y * w11;
    r.z = v00.z * w00 + v01.z * w01 + v10.z * w10 + v11.z * w11;
    r.w = v00.w * w00 + v01.w * w01 + v10.w * w10 + v11.w * w11;

    out[(long)s * kC4 + q] = r;
}

extern "C" void kernel_launch(void* const* d_in, const int* in_sizes, int n_in,
                              void* d_out, int out_size, void* d_ws, size_t ws_size,
                              hipStream_t stream) {
    const float* data  = (const float*)d_in[0];
    const float* sub_x = (const float*)d_in[1];
    const float* sub_y = (const float*)d_in[2];
    float* out = (float*)d_out;

    int n_samples = in_sizes[1];            // N * P = 524288
    long total_threads = (long)n_samples * 8;
    int block = 256;
    int grid = (int)((total_threads + block - 1) / block);

    interp_kernel<<<grid, block, 0, stream>>>(
        (const float4*)data, sub_x, sub_y, (float4*)out, n_samples);
}